// Round 7
// baseline (19152.409 us; speedup 1.0000x reference)
//
#include <hip/hip_runtime.h>
#include <hip/hip_fp16.h>

#define T_DATA 50000
#define E_NO 2000
#define I_NO 500
#define NS 10
#define NB 19
#define NT 100
#define T_PADR 50016         // pre rows incl. prefetch overrun pad

// workspace layout (bytes) — total 1,018,752 (R5/R6 full path proves ws >= 1.23MB)
#define OFF_H     0           // f32 [10][128]
#define OFF_EK    5120        // f32 [10][128]
#define OFF_IK    10240       // f32 [10][128]
#define OFF_WP    15360       // f32 [32]
#define OFF_AE    15488       // u8  [2000] (pad 2048)
#define OFF_AI    17536       // u8  [500]  (pad 512)
#define OFF_FLAGS 18048       // i32 [2]: {dtype 0=f32/1=bf16/2=f16, swap}
#define OFF_PRE   18112       // f16 [50016][10] = 1000320
#define WS_NEED   1018432u

// dtype-flexible scalar load (belt-and-braces; dt=0 expected)
__device__ __forceinline__ float loadF(const void* p, long i, int dt) {
    if (dt == 0) return ((const float*)p)[i];
    if (dt == 1) {
        unsigned v = (unsigned)((const unsigned short*)p)[i] << 16;
        return __uint_as_float(v);
    }
    return __half2float(((const __half*)p)[i]);
}

// ---------------------------------------------------------------------------
// Kernel 0: dtype/swap probe. W_sub is exactly 0.5 x10 by construction;
// Theta = 0.05*normal can never bit-match. Resolves the two size-10 inputs.
// ---------------------------------------------------------------------------
__global__ void probe_kernel(const unsigned* cand0, const unsigned* cand1,
                             int* flags)
{
    unsigned a = cand0[0], b = cand1[0];
    int ca = -1, cb = -1;
    if (a == 0x3F000000u) ca = 0; else if (a == 0x3F003F00u) ca = 1;
    else if (a == 0x38003800u) ca = 2;
    if (b == 0x3F000000u) cb = 0; else if (b == 0x3F003F00u) cb = 1;
    else if (b == 0x38003800u) cb = 2;
    int dt, sw;
    if (ca >= 0)      { dt = ca; sw = 0; }
    else if (cb >= 0) { dt = cb; sw = 1; }
    else              { dt = 0;  sw = 0; }   // fallback: f32, dict order
    flags[0] = dt; flags[1] = sw;
}

// ---------------------------------------------------------------------------
// Kernel A: filters (written f32 DIRECTLY to out+50000) / assignment tables /
// prop weights (1 block)
// ---------------------------------------------------------------------------
__global__ __launch_bounds__(256) void prep_kernel(
    const void* __restrict__ W_syn,   // [10][19][2]
    const void* __restrict__ W_hist,  // [10][19]
    const void* __restrict__ ws_c0,   // size-10 slot A (dict-order W_sub)
    const void* __restrict__ ws_c1,   // size-10 slot B (dict-order Theta)
    const void* __restrict__ C_den,   // [10][10]
    const void* __restrict__ C_syn_e, // [10][2000]
    const void* __restrict__ C_syn_i, // [10][500]
    const int* __restrict__ flags,
    unsigned char* __restrict__ ws,
    float* __restrict__ out_filters)  // d_out + 50000, f32 [30][100]
{
    const int dt = flags[0];
    const void* W_sub = flags[1] ? ws_c1 : ws_c0;
    float* h_r  = (float*)(ws + OFF_H);
    float* ek   = (float*)(ws + OFF_EK);
    float* ik   = (float*)(ws + OFF_IK);
    float* wp   = (float*)(ws + OFF_WP);
    unsigned char* ae = ws + OFF_AE;
    unsigned char* ai = ws + OFF_AI;
    const int tid = threadIdx.x;
    const float PI  = 3.14159265358979323846f;
    const float HPI = 1.57079632679489662f;

    // rows 0-9 e_kern, 10-19 i_kern, 20-29 hist_kern
    for (int idx = tid; idx < 3000; idx += 256) {
        int row = idx / 100, x = idx % 100;
        int typ = row / 10, s = row % 10;
        float raw = 5.0f * logf((float)x + 1.0f);
        float acc = 0.0f;
        for (int b = 0; b < NB; ++b) {
            float phi = HPI * (float)b;
            float d = raw - phi;
            if (d >= -PI && d <= PI) {
                float w;
                if (typ == 0)      w = loadF(W_syn, (long)(s*NB + b)*2 + 0, dt);
                else if (typ == 1) w = loadF(W_syn, (long)(s*NB + b)*2 + 1, dt);
                else               w = loadF(W_hist, (long)(s*NB + b), dt);
                acc = fmaf(w, 0.5f * cosf(d) + 0.5f, acc);
            }
        }
        out_filters[row*100 + x] = acc;          // f32 output, direct
        if (typ == 0)      ek[s*128 + x] = acc;
        else if (typ == 1) ik[s*128 + x] = acc;
        else               h_r[s*128 + x] = acc;
    }
    for (int e = tid; e < E_NO; e += 256) {
        unsigned char a = 0;
        for (int s = 0; s < NS; ++s)
            if (loadF(C_syn_e, (long)s*E_NO + e, dt) > 0.5f) a = (unsigned char)s;
        ae[e] = a;
    }
    for (int e = tid; e < I_NO; e += 256) {
        unsigned char a = 0;
        for (int s = 0; s < NS; ++s)
            if (loadF(C_syn_i, (long)s*I_NO + e, dt) > 0.5f) a = (unsigned char)s;
        ai[e] = a;
    }
    if (tid < NS) {
        int s = tid;
        int c1 = 2*s + 1, c2 = 2*s + 2;
        float v1 = 0.f, v2 = 0.f;
        if (c1 < NS) { float w = loadF(W_sub, c1, dt); v1 = loadF(C_den, s*NS + c1, dt) * w * w; }
        if (c2 < NS) { float w = loadF(W_sub, c2, dt); v2 = loadF(C_den, s*NS + c2, dt) * w * w; }
        wp[2*s] = v1; wp[2*s + 1] = v2;
    }
}

// ---------------------------------------------------------------------------
// Kernel B (fused agg + conv): aggregate 355-row spike window into LDS,
// then causal filter + Theta -> pre[t][s] f16.
// ---------------------------------------------------------------------------
__global__ __launch_bounds__(256) void convf_kernel(
    const void* __restrict__ S_e,
    const void* __restrict__ S_i,
    const unsigned char* __restrict__ ae,
    const unsigned char* __restrict__ ai,
    const float* __restrict__ ek,
    const float* __restrict__ ik,
    const void* __restrict__ th_c0,
    const void* __restrict__ th_c1,
    const int* __restrict__ flags,
    __half* __restrict__ pre)
{
    __shared__ float se[355][11];
    __shared__ float si[355][11];
    __shared__ float k_e[NS][NT];
    __shared__ float k_i[NS][NT];
    const int dt = flags[0];
    const void* Theta = flags[1] ? th_c0 : th_c1;   // Theta = non-W_sub slot
    const int tid = threadIdx.x;
    const int T0 = blockIdx.x * 256;

    for (int idx = tid; idx < NS*NT; idx += 256) {
        int s = idx / NT, u = idx % NT;
        k_e[s][u] = ek[s*128 + u];
        k_i[s][u] = ik[s*128 + u];
    }
    for (int idx = tid; idx < 355*11; idx += 256) {
        (&se[0][0])[idx] = 0.f;
        (&si[0][0])[idx] = 0.f;
    }
    __syncthreads();

    if (dt == 0) {
        // f32 spikes: E row = 500 uint4 (4 elems), I row = 125 uint4
        for (int w = tid; w < 355*500; w += 256) {
            int rr = w / 500, c = w - rr*500;
            int t = T0 - 99 + rr;
            if (t < 0 || t >= T_DATA) continue;
            uint4 v = ((const uint4*)((const float*)S_e + (size_t)t * E_NO))[c];
            if (v.x | v.y | v.z | v.w) {
                int e0 = c * 4;
                if (v.x) atomicAdd(&se[rr][ae[e0 + 0]], 1.0f);
                if (v.y) atomicAdd(&se[rr][ae[e0 + 1]], 1.0f);
                if (v.z) atomicAdd(&se[rr][ae[e0 + 2]], 1.0f);
                if (v.w) atomicAdd(&se[rr][ae[e0 + 3]], 1.0f);
            }
        }
        for (int w = tid; w < 355*125; w += 256) {
            int rr = w / 125, c = w - rr*125;
            int t = T0 - 99 + rr;
            if (t < 0 || t >= T_DATA) continue;
            uint4 v = ((const uint4*)((const float*)S_i + (size_t)t * I_NO))[c];
            if (v.x | v.y | v.z | v.w) {
                int e0 = c * 4;
                if (v.x) atomicAdd(&si[rr][ai[e0 + 0]], 1.0f);
                if (v.y) atomicAdd(&si[rr][ai[e0 + 1]], 1.0f);
                if (v.z) atomicAdd(&si[rr][ai[e0 + 2]], 1.0f);
                if (v.w) atomicAdd(&si[rr][ai[e0 + 3]], 1.0f);
            }
        }
    } else {
        // 16-bit spikes (unused if dt=0): E row = 250 uint4, I row = 125 uint2
        for (int w = tid; w < 355*250; w += 256) {
            int rr = w / 250, c = w - rr*250;
            int t = T0 - 99 + rr;
            if (t < 0 || t >= T_DATA) continue;
            uint4 v = ((const uint4*)((const unsigned short*)S_e + (size_t)t * E_NO))[c];
            if (v.x | v.y | v.z | v.w) {
                int e0 = c * 8;
                #pragma unroll
                for (int q = 0; q < 4; ++q) {
                    unsigned wv = (&v.x)[q];
                    if (wv & 0xffffu) atomicAdd(&se[rr][ae[e0 + 2*q]], 1.0f);
                    if (wv >> 16)     atomicAdd(&se[rr][ae[e0 + 2*q + 1]], 1.0f);
                }
            }
        }
        for (int w = tid; w < 355*125; w += 256) {
            int rr = w / 125, c = w - rr*125;
            int t = T0 - 99 + rr;
            if (t < 0 || t >= T_DATA) continue;
            uint2 v = ((const uint2*)((const unsigned short*)S_i + (size_t)t * I_NO))[c];
            if (v.x | v.y) {
                int e0 = c * 4;
                if (v.x & 0xffffu) atomicAdd(&si[rr][ai[e0 + 0]], 1.0f);
                if (v.x >> 16)     atomicAdd(&si[rr][ai[e0 + 1]], 1.0f);
                if (v.y & 0xffffu) atomicAdd(&si[rr][ai[e0 + 2]], 1.0f);
                if (v.y >> 16)     atomicAdd(&si[rr][ai[e0 + 3]], 1.0f);
            }
        }
    }
    __syncthreads();
    const int t = T0 + tid;
    if (t >= T_PADR) return;
    if (t >= T_DATA) {           // zero pad rows for scan's prefetch overrun
        for (int s = 0; s < NS; ++s) pre[(size_t)t*NS + s] = __float2half(0.0f);
        return;
    }
    const int lt = tid + 99;
    float accs[NS];
    #pragma unroll
    for (int s = 0; s < NS; ++s) accs[s] = 0.f;
    for (int u = 0; u < NT; ++u) {
        #pragma unroll
        for (int s = 0; s < NS; ++s)
            accs[s] += k_e[s][u]*se[lt - u][s] + k_i[s][u]*si[lt - u][s];
    }
    #pragma unroll
    for (int s = 0; s < NS; ++s)
        pre[(size_t)t*NS + s] = __float2half(accs[s] + loadF(Theta, s, dt));
}

// ---------------------------------------------------------------------------
// Kernel C: serial scan, single wave, gather form. V written f32 DIRECTLY
// to out[0..50000). Lanes (jj,s): jj=lane/10 (0..5 active), s=lane%10.
// Per step t, lane (jj,s) sums taps j=jj+6m (m<17, j<100):
// hreg[m]*ring[(t-1-j)&127][s]; 3-shfl reduce over jj; chain lanes (jj==0)
// tanh, write ring; lane 0 writes V.
// ---------------------------------------------------------------------------
__global__ __launch_bounds__(64) void scan_kernel(
    const __half* __restrict__ pre,
    const float* __restrict__ h_r,
    const float* __restrict__ wp,
    const void* __restrict__ ws_c0,
    const void* __restrict__ ws_c1,
    const void* __restrict__ V_o,
    const int* __restrict__ flags,
    float* __restrict__ outV)
{
    __shared__ float ring[128][NS];
    const int dt = flags[0];
    const void* W_sub = flags[1] ? ws_c1 : ws_c0;
    const int lane = threadIdx.x & 63;
    const int s  = lane % NS;
    const int jj = lane / NS;        // 0..6 (lanes 60-63 contribute zeros)
    const bool act   = lane < 60;
    const bool chain = (jj == 0);

    for (int i = lane; i < 128*NS; i += 64) (&ring[0][0])[i] = 0.f;
    __syncthreads();

    float hreg[17];
    #pragma unroll
    for (int m = 0; m < 17; ++m) {
        int j = jj + 6*m;
        hreg[m] = (act && j < NT) ? h_r[s*128 + j] : 0.f;
    }
    const float w1  = wp[2*s];
    const float w2v = wp[2*s + 1];
    const int c1 = (2*s + 1 < NS) ? (2*s + 1) : 0;
    const int c2 = (2*s + 2 < NS) ? (2*s + 2) : 0;
    const float Vo  = loadF(V_o, 0, dt);
    const float w0  = loadF(W_sub, 0, dt);
    const float W20 = w0 * w0;

    float ldn[16], ldc[16], propc[16];
    #pragma unroll
    for (int i = 0; i < 16; ++i) ldn[i] = __half2float(pre[i*NS + s]);

    for (int t0 = 0; t0 < T_DATA; t0 += 16) {
        #pragma unroll
        for (int i = 0; i < 16; ++i) ldc[i] = ldn[i];
        #pragma unroll
        for (int i = 0; i < 16; ++i)
            ldn[i] = __half2float(pre[(size_t)(t0 + 16 + i)*NS + s]);  // <=50015
        #pragma unroll
        for (int i = 0; i < 16; ++i) {
            int r = (t0 + i + 28) & 127;            // (t-100) mod 128
            propc[i] = fmaf(w1, ring[r][c1], w2v * ring[r][c2]);
        }
        #pragma unroll
        for (int i = 0; i < 16; ++i) {
            const int t = t0 + i;
            float p0 = 0.f, p1 = 0.f, p2 = 0.f, p3 = 0.f;
            #pragma unroll
            for (int m = 0; m < 17; m += 4) {
                p0 = fmaf(hreg[m], ring[(t - 1 - (jj + 6*m)) & 127][s], p0);
                if (m + 1 < 17) p1 = fmaf(hreg[m+1], ring[(t - 7 - (jj + 6*m)) & 127][s], p1);
                if (m + 2 < 17) p2 = fmaf(hreg[m+2], ring[(t - 13 - (jj + 6*m)) & 127][s], p2);
                if (m + 3 < 17) p3 = fmaf(hreg[m+3], ring[(t - 19 - (jj + 6*m)) & 127][s], p3);
            }
            float p = (p0 + p1) + (p2 + p3);
            float a = p + __shfl_down(p, 30);
            float total = a + __shfl_down(a, 10) + __shfl_down(a, 20);
            float x = ldc[i] + total + propc[i];
            float nv = tanhf(x);
            if (chain) ring[t & 127][s] = nv;
            if (lane == 0) outV[t] = fmaf(nv, W20, Vo);
        }
    }
}

__global__ __launch_bounds__(256) void zero_out_kernel(float* out) {
    int i = blockIdx.x * 256 + threadIdx.x;
    if (i < T_DATA + 3000) out[i] = 0.0f;
}

// ---------------------------------------------------------------------------
extern "C" void kernel_launch(void* const* d_in, const int* in_sizes, int n_in,
                              void* d_out, int out_size, void* d_ws, size_t ws_size,
                              hipStream_t stream)
{
    unsigned char* ws = (unsigned char*)d_ws;
    float* out = (float*)d_out;    // OUTPUT IS FLOAT32 (R5/R6 post-mortem)

    // role order: S_e, S_i, C_den, C_syn_e, C_syn_i, W_syn, W_hist,
    //             W_sub(1st size-10), V_o, Theta(2nd size-10)
    static const long EXP[10] = {100000000L, 25000000L, 100, 20000, 5000,
                                 380, 190, 10, 1, 10};
    int idx[10];
    bool ok = (n_in == 10);
    if (ok) {
        bool direct = true;
        for (int k = 0; k < 10; ++k)
            if ((long)in_sizes[k] != EXP[k]) { direct = false; break; }
        if (direct) {
            for (int k = 0; k < 10; ++k) idx[k] = k;
        } else {
            bool used[10] = {false,false,false,false,false,false,false,false,false,false};
            for (int k = 0; k < 10 && ok; ++k) {
                idx[k] = -1;
                for (int j = 0; j < 10; ++j)
                    if (!used[j] && (long)in_sizes[j] == EXP[k]) {
                        idx[k] = j; used[j] = true; break;
                    }
                if (idx[k] < 0) ok = false;
            }
        }
    }
    if (!ok || ws_size < (size_t)WS_NEED) {
        zero_out_kernel<<<208, 256, 0, stream>>>(out);
        return;
    }
    const void* S_e     = d_in[idx[0]];
    const void* S_i     = d_in[idx[1]];
    const void* C_den   = d_in[idx[2]];
    const void* C_syn_e = d_in[idx[3]];
    const void* C_syn_i = d_in[idx[4]];
    const void* W_syn   = d_in[idx[5]];
    const void* Whist   = d_in[idx[6]];
    const void* Wsub0   = d_in[idx[7]];
    const void* V_o     = d_in[idx[8]];
    const void* Wsub1   = d_in[idx[9]];
    int* flags = (int*)(ws + OFF_FLAGS);

    probe_kernel<<<1, 1, 0, stream>>>((const unsigned*)Wsub0,
                                      (const unsigned*)Wsub1, flags);
    prep_kernel<<<1, 256, 0, stream>>>(W_syn, Whist, Wsub0, Wsub1,
                                       C_den, C_syn_e, C_syn_i, flags, ws,
                                       out + T_DATA);
    convf_kernel<<<196, 256, 0, stream>>>(
        S_e, S_i, ws + OFF_AE, ws + OFF_AI,
        (const float*)(ws + OFF_EK), (const float*)(ws + OFF_IK),
        Wsub0, Wsub1, flags, (__half*)(ws + OFF_PRE));
    scan_kernel<<<1, 64, 0, stream>>>(
        (const __half*)(ws + OFF_PRE),
        (const float*)(ws + OFF_H),
        (const float*)(ws + OFF_WP),
        Wsub0, Wsub1, V_o, flags, out);
}

// Round 8
// 6580.093 us; speedup vs baseline: 2.9107x; 2.9107x over previous
//
#include <hip/hip_runtime.h>
#include <hip/hip_fp16.h>

#define T_DATA 50000
#define E_NO 2000
#define I_NO 500
#define NS 10
#define NB 19
#define NT 100
#define T_PADR 50176         // pre rows incl. lookahead overrun (reads to 50131)
#define KSC 2.8853900817779268f   // 2/ln2: tanh(x) = 1 - 2/(exp2(KSC*x)+1)

// workspace layout (bytes) — total 1,021,632 (ws >= 1.23MB proven in R4-R7)
#define OFF_H     0           // f32 [10][128]  hist kern * KSC
#define OFF_EK    5120        // f32 [10][128]
#define OFF_IK    10240       // f32 [10][128]
#define OFF_WP    15360       // f32 [32]       prop weights * KSC
#define OFF_AE    15488       // u8  [2000] (pad 2048)
#define OFF_AI    17536       // u8  [500]  (pad 512)
#define OFF_FLAGS 18048       // i32 [2]: {dtype 0=f32/1=bf16/2=f16, swap}
#define OFF_PRE   18112       // f16 [50176][10] = 1003520, KSC-scaled
#define WS_NEED   1021632u

// dtype-flexible scalar load (belt-and-braces; dt=0 = f32 confirmed)
__device__ __forceinline__ float loadF(const void* p, long i, int dt) {
    if (dt == 0) return ((const float*)p)[i];
    if (dt == 1) {
        unsigned v = (unsigned)((const unsigned short*)p)[i] << 16;
        return __uint_as_float(v);
    }
    return __half2float(((const __half*)p)[i]);
}

// ---------------------------------------------------------------------------
// Kernel 0: dtype/swap probe. W_sub is exactly 0.5 x10 by construction.
// ---------------------------------------------------------------------------
__global__ void probe_kernel(const unsigned* cand0, const unsigned* cand1,
                             int* flags)
{
    unsigned a = cand0[0], b = cand1[0];
    int ca = -1, cb = -1;
    if (a == 0x3F000000u) ca = 0; else if (a == 0x3F003F00u) ca = 1;
    else if (a == 0x38003800u) ca = 2;
    if (b == 0x3F000000u) cb = 0; else if (b == 0x3F003F00u) cb = 1;
    else if (b == 0x38003800u) cb = 2;
    int dt, sw;
    if (ca >= 0)      { dt = ca; sw = 0; }
    else if (cb >= 0) { dt = cb; sw = 1; }
    else              { dt = 0;  sw = 0; }
    flags[0] = dt; flags[1] = sw;
}

// ---------------------------------------------------------------------------
// Kernel A: filters (f32 direct to out+50000) / assignments / prop weights
// h_r and wp stored KSC-SCALED for the exp2-form tanh in the scan.
// ---------------------------------------------------------------------------
__global__ __launch_bounds__(256) void prep_kernel(
    const void* __restrict__ W_syn,   // [10][19][2]
    const void* __restrict__ W_hist,  // [10][19]
    const void* __restrict__ ws_c0,   // size-10 slot A (dict-order W_sub)
    const void* __restrict__ ws_c1,   // size-10 slot B (dict-order Theta)
    const void* __restrict__ C_den,   // [10][10]
    const void* __restrict__ C_syn_e, // [10][2000]
    const void* __restrict__ C_syn_i, // [10][500]
    const int* __restrict__ flags,
    unsigned char* __restrict__ ws,
    float* __restrict__ out_filters)  // d_out + 50000, f32 [30][100]
{
    const int dt = flags[0];
    const void* W_sub = flags[1] ? ws_c1 : ws_c0;
    float* h_s  = (float*)(ws + OFF_H);
    float* ek   = (float*)(ws + OFF_EK);
    float* ik   = (float*)(ws + OFF_IK);
    float* wp   = (float*)(ws + OFF_WP);
    unsigned char* ae = ws + OFF_AE;
    unsigned char* ai = ws + OFF_AI;
    const int tid = threadIdx.x;
    const float PI  = 3.14159265358979323846f;
    const float HPI = 1.57079632679489662f;

    // rows 0-9 e_kern, 10-19 i_kern, 20-29 hist_kern
    for (int idx = tid; idx < 3000; idx += 256) {
        int row = idx / 100, x = idx % 100;
        int typ = row / 10, s = row % 10;
        float raw = 5.0f * logf((float)x + 1.0f);
        float acc = 0.0f;
        for (int b = 0; b < NB; ++b) {
            float phi = HPI * (float)b;
            float d = raw - phi;
            if (d >= -PI && d <= PI) {
                float w;
                if (typ == 0)      w = loadF(W_syn, (long)(s*NB + b)*2 + 0, dt);
                else if (typ == 1) w = loadF(W_syn, (long)(s*NB + b)*2 + 1, dt);
                else               w = loadF(W_hist, (long)(s*NB + b), dt);
                acc = fmaf(w, 0.5f * cosf(d) + 0.5f, acc);
            }
        }
        out_filters[row*100 + x] = acc;          // raw filters to output
        if (typ == 0)      ek[s*128 + x] = acc;
        else if (typ == 1) ik[s*128 + x] = acc;
        else               h_s[s*128 + x] = acc * KSC;   // scaled for scan
    }
    for (int e = tid; e < E_NO; e += 256) {
        unsigned char a = 0;
        for (int s = 0; s < NS; ++s)
            if (loadF(C_syn_e, (long)s*E_NO + e, dt) > 0.5f) a = (unsigned char)s;
        ae[e] = a;
    }
    for (int e = tid; e < I_NO; e += 256) {
        unsigned char a = 0;
        for (int s = 0; s < NS; ++s)
            if (loadF(C_syn_i, (long)s*I_NO + e, dt) > 0.5f) a = (unsigned char)s;
        ai[e] = a;
    }
    if (tid < NS) {
        int s = tid;
        int c1 = 2*s + 1, c2 = 2*s + 2;
        float v1 = 0.f, v2 = 0.f;
        if (c1 < NS) { float w = loadF(W_sub, c1, dt); v1 = KSC * loadF(C_den, s*NS + c1, dt) * w * w; }
        if (c2 < NS) { float w = loadF(W_sub, c2, dt); v2 = KSC * loadF(C_den, s*NS + c2, dt) * w * w; }
        wp[2*s] = v1; wp[2*s + 1] = v2;
    }
}

// ---------------------------------------------------------------------------
// Kernel B (fused agg + conv): aggregate 355-row spike window into LDS,
// then causal filter + Theta -> pre[t][s] f16, KSC-SCALED.
// ---------------------------------------------------------------------------
__global__ __launch_bounds__(256) void convf_kernel(
    const void* __restrict__ S_e,
    const void* __restrict__ S_i,
    const unsigned char* __restrict__ ae,
    const unsigned char* __restrict__ ai,
    const float* __restrict__ ek,
    const float* __restrict__ ik,
    const void* __restrict__ th_c0,
    const void* __restrict__ th_c1,
    const int* __restrict__ flags,
    __half* __restrict__ pre)
{
    __shared__ float se[355][11];
    __shared__ float si[355][11];
    __shared__ float k_e[NS][NT];
    __shared__ float k_i[NS][NT];
    const int dt = flags[0];
    const void* Theta = flags[1] ? th_c0 : th_c1;   // Theta = non-W_sub slot
    const int tid = threadIdx.x;
    const int T0 = blockIdx.x * 256;

    for (int idx = tid; idx < NS*NT; idx += 256) {
        int s = idx / NT, u = idx % NT;
        k_e[s][u] = ek[s*128 + u];
        k_i[s][u] = ik[s*128 + u];
    }
    for (int idx = tid; idx < 355*11; idx += 256) {
        (&se[0][0])[idx] = 0.f;
        (&si[0][0])[idx] = 0.f;
    }
    __syncthreads();

    if (dt == 0) {
        for (int w = tid; w < 355*500; w += 256) {
            int rr = w / 500, c = w - rr*500;
            int t = T0 - 99 + rr;
            if (t < 0 || t >= T_DATA) continue;
            uint4 v = ((const uint4*)((const float*)S_e + (size_t)t * E_NO))[c];
            if (v.x | v.y | v.z | v.w) {
                int e0 = c * 4;
                if (v.x) atomicAdd(&se[rr][ae[e0 + 0]], 1.0f);
                if (v.y) atomicAdd(&se[rr][ae[e0 + 1]], 1.0f);
                if (v.z) atomicAdd(&se[rr][ae[e0 + 2]], 1.0f);
                if (v.w) atomicAdd(&se[rr][ae[e0 + 3]], 1.0f);
            }
        }
        for (int w = tid; w < 355*125; w += 256) {
            int rr = w / 125, c = w - rr*125;
            int t = T0 - 99 + rr;
            if (t < 0 || t >= T_DATA) continue;
            uint4 v = ((const uint4*)((const float*)S_i + (size_t)t * I_NO))[c];
            if (v.x | v.y | v.z | v.w) {
                int e0 = c * 4;
                if (v.x) atomicAdd(&si[rr][ai[e0 + 0]], 1.0f);
                if (v.y) atomicAdd(&si[rr][ai[e0 + 1]], 1.0f);
                if (v.z) atomicAdd(&si[rr][ai[e0 + 2]], 1.0f);
                if (v.w) atomicAdd(&si[rr][ai[e0 + 3]], 1.0f);
            }
        }
    } else {
        for (int w = tid; w < 355*250; w += 256) {
            int rr = w / 250, c = w - rr*250;
            int t = T0 - 99 + rr;
            if (t < 0 || t >= T_DATA) continue;
            uint4 v = ((const uint4*)((const unsigned short*)S_e + (size_t)t * E_NO))[c];
            if (v.x | v.y | v.z | v.w) {
                int e0 = c * 8;
                #pragma unroll
                for (int q = 0; q < 4; ++q) {
                    unsigned wv = (&v.x)[q];
                    if (wv & 0xffffu) atomicAdd(&se[rr][ae[e0 + 2*q]], 1.0f);
                    if (wv >> 16)     atomicAdd(&se[rr][ae[e0 + 2*q + 1]], 1.0f);
                }
            }
        }
        for (int w = tid; w < 355*125; w += 256) {
            int rr = w / 125, c = w - rr*125;
            int t = T0 - 99 + rr;
            if (t < 0 || t >= T_DATA) continue;
            uint2 v = ((const uint2*)((const unsigned short*)S_i + (size_t)t * I_NO))[c];
            if (v.x | v.y) {
                int e0 = c * 4;
                if (v.x & 0xffffu) atomicAdd(&si[rr][ai[e0 + 0]], 1.0f);
                if (v.x >> 16)     atomicAdd(&si[rr][ai[e0 + 1]], 1.0f);
                if (v.y & 0xffffu) atomicAdd(&si[rr][ai[e0 + 2]], 1.0f);
                if (v.y >> 16)     atomicAdd(&si[rr][ai[e0 + 3]], 1.0f);
            }
        }
    }
    __syncthreads();
    const int t = T0 + tid;
    if (t >= T_PADR) return;
    if (t >= T_DATA) {           // zero pad rows for scan lookahead overrun
        for (int s = 0; s < NS; ++s) pre[(size_t)t*NS + s] = __float2half(0.0f);
        return;
    }
    const int lt = tid + 99;
    float accs[NS];
    #pragma unroll
    for (int s = 0; s < NS; ++s) accs[s] = 0.f;
    for (int u = 0; u < NT; ++u) {
        #pragma unroll
        for (int s = 0; s < NS; ++s)
            accs[s] += k_e[s][u]*se[lt - u][s] + k_i[s][u]*si[lt - u][s];
    }
    #pragma unroll
    for (int s = 0; s < NS; ++s)
        pre[(size_t)t*NS + s] = __float2half(KSC * (accs[s] + loadF(Theta, s, dt)));
}

// ---------------------------------------------------------------------------
// Kernel C: serial scan, single wave, SCATTER form.
// Lanes (g,s): g=lane/10 (0..5 active), s=lane%10. 1010 pending slots in
// registers: lane (g,s) holds pend[17]; at step t register k has local
// l=(k-t)%17, depth d=17g+l, target T=t+d, value = KSC*(pre[T]+taps j>d
// already applied). Per step: broadcast v=ns[t-1] (1 shfl, off critical
// path), handoff depth-boundary slot via shfl_down(10) (g=5 reborn from
// lookahead ld = pre[t+101]), apply one tap h[d]*v per slot (17 FMA),
// retire depth-0 on g=0: x = pend + prop + h0*nsv(lane-local); tanh via
// exp2/rcp (KSC pre-folded). prop for t+17 written into the freed propv[p].
// Critical cycle: fma->exp2->add->rcp->fma (~32cyc); issue ~35 instr/step.
// ---------------------------------------------------------------------------
__global__ __launch_bounds__(64) void scan_kernel(
    const __half* __restrict__ pre,
    const float* __restrict__ h_s,
    const float* __restrict__ wp,
    const void* __restrict__ ws_c0,
    const void* __restrict__ ws_c1,
    const void* __restrict__ V_o,
    const int* __restrict__ flags,
    float* __restrict__ outV)
{
    __shared__ float ring[128][NS];
    const int dt = flags[0];
    const void* W_sub = flags[1] ? ws_c1 : ws_c0;
    const int lane = threadIdx.x & 63;
    const int s = lane % NS;
    const int g = lane / NS;          // 0..6 (lanes 60-63 inactive)
    const bool active = (g < 6);
    const bool loader = (g == 5);
    const bool chain  = (g == 0);

    for (int i = lane; i < 128*NS; i += 64) (&ring[0][0])[i] = 0.f;
    __syncthreads();

    float hreg[17];
    #pragma unroll
    for (int k = 0; k < 17; ++k) {
        int j = 17*g + k;
        hreg[k] = (active && j < NT) ? h_s[s*128 + j] : 0.f;
    }
    // pend init = state at end of virtual step -1: reg k holds l=(k+1)%17,
    // T = 17g + l - 1, value pre[T] (no history exists yet).
    float pend[17];
    #pragma unroll
    for (int k = 0; k < 17; ++k) {
        int l = (k + 1) % 17;
        int T = 17*g + l - 1;
        pend[k] = (active && T >= 0) ? __half2float(pre[(size_t)T*NS + s]) : 0.f;
    }
    // lookahead: ld[j] first consumed at step t=(j+1)%17 as pre[t+101]
    float ld[17];
    #pragma unroll
    for (int j = 0; j < 17; ++j) {
        int T0 = (j == 16) ? 101 : (102 + j);
        ld[j] = __half2float(pre[(size_t)T0*NS + s]);
    }
    // propv[p] holds prop for the next step t with t%17==p (0 for t<100)
    float propv[17];
    #pragma unroll
    for (int q = 0; q < 17; ++q) propv[q] = 0.f;

    const float w1  = wp[2*s];
    const float w2v = wp[2*s + 1];
    const int c1 = (2*s + 1 < NS) ? (2*s + 1) : 0;
    const int c2 = (2*s + 2 < NS) ? (2*s + 2) : 0;
    const float Vo  = loadF(V_o, 0, dt);
    const float w0  = loadF(W_sub, 0, dt);
    const float W20 = w0 * w0;
    float nsv = 0.0f;

    const __half* pcur = pre + (size_t)118*NS + s;   // pre[t+118][s] at t=0

    for (int tb = 0; tb < T_DATA; tb += 17) {
        #pragma unroll
        for (int p = 0; p < 17; ++p) {
            const int t = tb + p;
            const int kw = (p + 16) % 17;
            // broadcast ns[t-1][s] from chain lane s (uses OLD nsv)
            float v = __shfl(nsv, s);
            // handoff: old pend[kw] (depth-17g slot) moves down a group;
            // g=5 reborn with pre[t+101]
            float up = __shfl_down(pend[kw], 10);
            pend[kw] = loader ? ld[kw] : up;
            // refill lookahead (consumed at step t+17 as pre[(t+17)+101])
            ld[kw] = __half2float(*pcur);
            pcur += NS;
            // retire: pend[p] complete for taps j>=1; add j=0 from
            // LANE-LOCAL nsv (== v on chain lanes), prop from propv[p]
            float x = fmaf(nsv, hreg[0], pend[p] + propv[p]);
            float e2 = __builtin_amdgcn_exp2f(x);
            float r  = __builtin_amdgcn_rcpf(e2 + 1.0f);
            float nv = fmaf(-2.0f, r, 1.0f);           // tanh
            // prop for step t+17 into the just-freed slot (ring row t-83)
            const int rr = (t + 45) & 127;
            propv[p] = fmaf(w1, ring[rr][c1], w2v * ring[rr][c2]);
            // scatter: reg (p+m)%17 has depth 17g+m -> tap h[17g+m]*v
            #pragma unroll
            for (int m = 0; m < 17; ++m) {
                const int k2 = (p + m) % 17;
                pend[k2] = fmaf(v, hreg[m], pend[k2]);
            }
            nsv = nv;
            if (chain) ring[t & 127][s] = nv;
            if (lane == 0 && t < T_DATA) outV[t] = fmaf(nv, W20, Vo);
        }
    }
}

__global__ __launch_bounds__(256) void zero_out_kernel(float* out) {
    int i = blockIdx.x * 256 + threadIdx.x;
    if (i < T_DATA + 3000) out[i] = 0.0f;
}

// ---------------------------------------------------------------------------
extern "C" void kernel_launch(void* const* d_in, const int* in_sizes, int n_in,
                              void* d_out, int out_size, void* d_ws, size_t ws_size,
                              hipStream_t stream)
{
    unsigned char* ws = (unsigned char*)d_ws;
    float* out = (float*)d_out;    // output is float32 (R7 confirmed)

    static const long EXP[10] = {100000000L, 25000000L, 100, 20000, 5000,
                                 380, 190, 10, 1, 10};
    int idx[10];
    bool ok = (n_in == 10);
    if (ok) {
        bool direct = true;
        for (int k = 0; k < 10; ++k)
            if ((long)in_sizes[k] != EXP[k]) { direct = false; break; }
        if (direct) {
            for (int k = 0; k < 10; ++k) idx[k] = k;
        } else {
            bool used[10] = {false,false,false,false,false,false,false,false,false,false};
            for (int k = 0; k < 10 && ok; ++k) {
                idx[k] = -1;
                for (int j = 0; j < 10; ++j)
                    if (!used[j] && (long)in_sizes[j] == EXP[k]) {
                        idx[k] = j; used[j] = true; break;
                    }
                if (idx[k] < 0) ok = false;
            }
        }
    }
    if (!ok || ws_size < (size_t)WS_NEED) {
        zero_out_kernel<<<208, 256, 0, stream>>>(out);
        return;
    }
    const void* S_e     = d_in[idx[0]];
    const void* S_i     = d_in[idx[1]];
    const void* C_den   = d_in[idx[2]];
    const void* C_syn_e = d_in[idx[3]];
    const void* C_syn_i = d_in[idx[4]];
    const void* W_syn   = d_in[idx[5]];
    const void* Whist   = d_in[idx[6]];
    const void* Wsub0   = d_in[idx[7]];
    const void* V_o     = d_in[idx[8]];
    const void* Wsub1   = d_in[idx[9]];
    int* flags = (int*)(ws + OFF_FLAGS);

    probe_kernel<<<1, 1, 0, stream>>>((const unsigned*)Wsub0,
                                      (const unsigned*)Wsub1, flags);
    prep_kernel<<<1, 256, 0, stream>>>(W_syn, Whist, Wsub0, Wsub1,
                                       C_den, C_syn_e, C_syn_i, flags, ws,
                                       out + T_DATA);
    convf_kernel<<<196, 256, 0, stream>>>(
        S_e, S_i, ws + OFF_AE, ws + OFF_AI,
        (const float*)(ws + OFF_EK), (const float*)(ws + OFF_IK),
        Wsub0, Wsub1, flags, (__half*)(ws + OFF_PRE));
    scan_kernel<<<1, 64, 0, stream>>>(
        (const __half*)(ws + OFF_PRE),
        (const float*)(ws + OFF_H),
        (const float*)(ws + OFF_WP),
        Wsub0, Wsub1, V_o, flags, out);
}

// Round 9
// 5931.631 us; speedup vs baseline: 3.2289x; 1.1093x over previous
//
#include <hip/hip_runtime.h>
#include <hip/hip_fp16.h>

#define T_DATA 50000
#define E_NO 2000
#define I_NO 500
#define NS 10
#define NB 19
#define NT 100
#define T_PADR 50176         // pre rows incl. lookahead overrun (reads to 50131)
#define KSC 2.8853900817779268f   // 2/ln2: tanh(x) = 1 - 2/(exp2(KSC*x)+1)

// workspace layout (bytes)
#define OFF_H     0           // f32 [10][128]  hist kern * KSC
#define OFF_EK    5120        // f32 [10][128]
#define OFF_IK    10240       // f32 [10][128]
#define OFF_WP    15360       // f32 [32]       prop weights * KSC
#define OFF_AE    15488       // u8  [2000] (pad 2048)
#define OFF_AI    17536       // u8  [500]  (pad 512)
#define OFF_FLAGS 18048       // i32 [2]
#define OFF_PRE   18112       // f16 [50176][10] = 1003520, KSC-scaled
#define WS_NEED   1021632u

__device__ __forceinline__ float loadF(const void* p, long i, int dt) {
    if (dt == 0) return ((const float*)p)[i];
    if (dt == 1) {
        unsigned v = (unsigned)((const unsigned short*)p)[i] << 16;
        return __uint_as_float(v);
    }
    return __half2float(((const __half*)p)[i]);
}

// ---------------------------------------------------------------------------
__global__ void probe_kernel(const unsigned* cand0, const unsigned* cand1,
                             int* flags)
{
    unsigned a = cand0[0], b = cand1[0];
    int ca = -1, cb = -1;
    if (a == 0x3F000000u) ca = 0; else if (a == 0x3F003F00u) ca = 1;
    else if (a == 0x38003800u) ca = 2;
    if (b == 0x3F000000u) cb = 0; else if (b == 0x3F003F00u) cb = 1;
    else if (b == 0x38003800u) cb = 2;
    int dt, sw;
    if (ca >= 0)      { dt = ca; sw = 0; }
    else if (cb >= 0) { dt = cb; sw = 1; }
    else              { dt = 0;  sw = 0; }
    flags[0] = dt; flags[1] = sw;
}

// ---------------------------------------------------------------------------
__global__ __launch_bounds__(256) void prep_kernel(
    const void* __restrict__ W_syn,
    const void* __restrict__ W_hist,
    const void* __restrict__ ws_c0,
    const void* __restrict__ ws_c1,
    const void* __restrict__ C_den,
    const void* __restrict__ C_syn_e,
    const void* __restrict__ C_syn_i,
    const int* __restrict__ flags,
    unsigned char* __restrict__ ws,
    float* __restrict__ out_filters)  // d_out + 50000, f32 [30][100]
{
    const int dt = flags[0];
    const void* W_sub = flags[1] ? ws_c1 : ws_c0;
    float* h_s  = (float*)(ws + OFF_H);
    float* ek   = (float*)(ws + OFF_EK);
    float* ik   = (float*)(ws + OFF_IK);
    float* wp   = (float*)(ws + OFF_WP);
    unsigned char* ae = ws + OFF_AE;
    unsigned char* ai = ws + OFF_AI;
    const int tid = threadIdx.x;
    const float PI  = 3.14159265358979323846f;
    const float HPI = 1.57079632679489662f;

    for (int idx = tid; idx < 3000; idx += 256) {
        int row = idx / 100, x = idx % 100;
        int typ = row / 10, s = row % 10;
        float raw = 5.0f * logf((float)x + 1.0f);
        float acc = 0.0f;
        for (int b = 0; b < NB; ++b) {
            float phi = HPI * (float)b;
            float d = raw - phi;
            if (d >= -PI && d <= PI) {
                float w;
                if (typ == 0)      w = loadF(W_syn, (long)(s*NB + b)*2 + 0, dt);
                else if (typ == 1) w = loadF(W_syn, (long)(s*NB + b)*2 + 1, dt);
                else               w = loadF(W_hist, (long)(s*NB + b), dt);
                acc = fmaf(w, 0.5f * cosf(d) + 0.5f, acc);
            }
        }
        out_filters[row*100 + x] = acc;
        if (typ == 0)      ek[s*128 + x] = acc;
        else if (typ == 1) ik[s*128 + x] = acc;
        else               h_s[s*128 + x] = acc * KSC;
    }
    for (int e = tid; e < E_NO; e += 256) {
        unsigned char a = 0;
        for (int s = 0; s < NS; ++s)
            if (loadF(C_syn_e, (long)s*E_NO + e, dt) > 0.5f) a = (unsigned char)s;
        ae[e] = a;
    }
    for (int e = tid; e < I_NO; e += 256) {
        unsigned char a = 0;
        for (int s = 0; s < NS; ++s)
            if (loadF(C_syn_i, (long)s*I_NO + e, dt) > 0.5f) a = (unsigned char)s;
        ai[e] = a;
    }
    if (tid < NS) {
        int s = tid;
        int c1 = 2*s + 1, c2 = 2*s + 2;
        float v1 = 0.f, v2 = 0.f;
        if (c1 < NS) { float w = loadF(W_sub, c1, dt); v1 = KSC * loadF(C_den, s*NS + c1, dt) * w * w; }
        if (c2 < NS) { float w = loadF(W_sub, c2, dt); v2 = KSC * loadF(C_den, s*NS + c2, dt) * w * w; }
        wp[2*s] = v1; wp[2*s + 1] = v2;
    }
}

// ---------------------------------------------------------------------------
// Kernel B (fused agg + conv). Interior blocks: contiguous streaming load
// (base[w]) with lazy index math only on (rare) spike hits.
// ---------------------------------------------------------------------------
__global__ __launch_bounds__(256) void convf_kernel(
    const void* __restrict__ S_e,
    const void* __restrict__ S_i,
    const unsigned char* __restrict__ ae,
    const unsigned char* __restrict__ ai,
    const float* __restrict__ ek,
    const float* __restrict__ ik,
    const void* __restrict__ th_c0,
    const void* __restrict__ th_c1,
    const int* __restrict__ flags,
    __half* __restrict__ pre)
{
    __shared__ float se[355][11];
    __shared__ float si[355][11];
    __shared__ float k_e[NS][NT];
    __shared__ float k_i[NS][NT];
    const int dt = flags[0];
    const void* Theta = flags[1] ? th_c0 : th_c1;
    const int tid = threadIdx.x;
    const int T0 = blockIdx.x * 256;

    for (int idx = tid; idx < NS*NT; idx += 256) {
        int s = idx / NT, u = idx % NT;
        k_e[s][u] = ek[s*128 + u];
        k_i[s][u] = ik[s*128 + u];
    }
    for (int idx = tid; idx < 355*11; idx += 256) {
        (&se[0][0])[idx] = 0.f;
        (&si[0][0])[idx] = 0.f;
    }
    __syncthreads();

    const bool interior = (T0 >= 99) && (T0 + 256 <= T_DATA);
    if (dt == 0) {
        if (interior) {
            const uint4* baseE = (const uint4*)((const float*)S_e + (size_t)(T0-99)*E_NO);
            for (int w = tid; w < 355*500; w += 256) {
                uint4 v = baseE[w];
                if (v.x | v.y | v.z | v.w) {
                    int rr = w / 500, e0 = (w - rr*500) * 4;
                    if (v.x) atomicAdd(&se[rr][ae[e0 + 0]], 1.0f);
                    if (v.y) atomicAdd(&se[rr][ae[e0 + 1]], 1.0f);
                    if (v.z) atomicAdd(&se[rr][ae[e0 + 2]], 1.0f);
                    if (v.w) atomicAdd(&se[rr][ae[e0 + 3]], 1.0f);
                }
            }
            const uint4* baseI = (const uint4*)((const float*)S_i + (size_t)(T0-99)*I_NO);
            for (int w = tid; w < 355*125; w += 256) {
                uint4 v = baseI[w];
                if (v.x | v.y | v.z | v.w) {
                    int rr = w / 125, e0 = (w - rr*125) * 4;
                    if (v.x) atomicAdd(&si[rr][ai[e0 + 0]], 1.0f);
                    if (v.y) atomicAdd(&si[rr][ai[e0 + 1]], 1.0f);
                    if (v.z) atomicAdd(&si[rr][ai[e0 + 2]], 1.0f);
                    if (v.w) atomicAdd(&si[rr][ai[e0 + 3]], 1.0f);
                }
            }
        } else {
            for (int w = tid; w < 355*500; w += 256) {
                int rr = w / 500, c = w - rr*500;
                int t = T0 - 99 + rr;
                if (t < 0 || t >= T_DATA) continue;
                uint4 v = ((const uint4*)((const float*)S_e + (size_t)t * E_NO))[c];
                if (v.x | v.y | v.z | v.w) {
                    int e0 = c * 4;
                    if (v.x) atomicAdd(&se[rr][ae[e0 + 0]], 1.0f);
                    if (v.y) atomicAdd(&se[rr][ae[e0 + 1]], 1.0f);
                    if (v.z) atomicAdd(&se[rr][ae[e0 + 2]], 1.0f);
                    if (v.w) atomicAdd(&se[rr][ae[e0 + 3]], 1.0f);
                }
            }
            for (int w = tid; w < 355*125; w += 256) {
                int rr = w / 125, c = w - rr*125;
                int t = T0 - 99 + rr;
                if (t < 0 || t >= T_DATA) continue;
                uint4 v = ((const uint4*)((const float*)S_i + (size_t)t * I_NO))[c];
                if (v.x | v.y | v.z | v.w) {
                    int e0 = c * 4;
                    if (v.x) atomicAdd(&si[rr][ai[e0 + 0]], 1.0f);
                    if (v.y) atomicAdd(&si[rr][ai[e0 + 1]], 1.0f);
                    if (v.z) atomicAdd(&si[rr][ai[e0 + 2]], 1.0f);
                    if (v.w) atomicAdd(&si[rr][ai[e0 + 3]], 1.0f);
                }
            }
        }
    } else {
        for (int w = tid; w < 355*250; w += 256) {
            int rr = w / 250, c = w - rr*250;
            int t = T0 - 99 + rr;
            if (t < 0 || t >= T_DATA) continue;
            uint4 v = ((const uint4*)((const unsigned short*)S_e + (size_t)t * E_NO))[c];
            if (v.x | v.y | v.z | v.w) {
                int e0 = c * 8;
                #pragma unroll
                for (int q = 0; q < 4; ++q) {
                    unsigned wv = (&v.x)[q];
                    if (wv & 0xffffu) atomicAdd(&se[rr][ae[e0 + 2*q]], 1.0f);
                    if (wv >> 16)     atomicAdd(&se[rr][ae[e0 + 2*q + 1]], 1.0f);
                }
            }
        }
        for (int w = tid; w < 355*125; w += 256) {
            int rr = w / 125, c = w - rr*125;
            int t = T0 - 99 + rr;
            if (t < 0 || t >= T_DATA) continue;
            uint2 v = ((const uint2*)((const unsigned short*)S_i + (size_t)t * I_NO))[c];
            if (v.x | v.y) {
                int e0 = c * 4;
                if (v.x & 0xffffu) atomicAdd(&si[rr][ai[e0 + 0]], 1.0f);
                if (v.x >> 16)     atomicAdd(&si[rr][ai[e0 + 1]], 1.0f);
                if (v.y & 0xffffu) atomicAdd(&si[rr][ai[e0 + 2]], 1.0f);
                if (v.y >> 16)     atomicAdd(&si[rr][ai[e0 + 3]], 1.0f);
            }
        }
    }
    __syncthreads();
    const int t = T0 + tid;
    if (t >= T_PADR) return;
    if (t >= T_DATA) {
        for (int s = 0; s < NS; ++s) pre[(size_t)t*NS + s] = __float2half(0.0f);
        return;
    }
    const int lt = tid + 99;
    float accs[NS];
    #pragma unroll
    for (int s = 0; s < NS; ++s) accs[s] = 0.f;
    for (int u = 0; u < NT; ++u) {
        #pragma unroll
        for (int s = 0; s < NS; ++s)
            accs[s] += k_e[s][u]*se[lt - u][s] + k_i[s][u]*si[lt - u][s];
    }
    #pragma unroll
    for (int s = 0; s < NS; ++s)
        pre[(size_t)t*NS + s] = __float2half(KSC * (accs[s] + loadF(Theta, s, dt)));
}

// ---------------------------------------------------------------------------
// Kernel C: serial scan, single wave, scatter form with DELAYED cross-lane.
// All ds-pipe ops (3 bpermute broadcasts + 1 handoff shfl) are issued 2 steps
// before consumption -> no lgkmcnt stalls (R8 was 270cy/step from 2 exposed
// ~120cy LDS latencies; this removes them).
//   - scatter at step t uses vdA = ns[t-3]: tap j = depth+2 (hreg[m]=h[17g+2+m])
//   - taps j=0,1 applied at retire from lane-local nsv, n1 (chain lanes)
//   - handoff staged when slot at l=1 on upper lane (consumed 2 steps later);
//     missed transit tap j=17g+19 compensated post-wrap using vdC = ns[t-4]
//   - prop scattered into depth-97 slot on loader lanes via vc1/vc2 delayed
//     broadcasts (w*ns[T-100] exact); NO LDS ring at all.
// ---------------------------------------------------------------------------
__global__ __launch_bounds__(64) void scan_kernel(
    const __half* __restrict__ pre,
    const float* __restrict__ h_s,
    const float* __restrict__ wp,
    const void* __restrict__ ws_c0,
    const void* __restrict__ ws_c1,
    const void* __restrict__ V_o,
    const int* __restrict__ flags,
    float* __restrict__ outV)
{
    const int dt = flags[0];
    const void* W_sub = flags[1] ? ws_c1 : ws_c0;
    const int lane = threadIdx.x & 63;
    const int s = lane % NS;
    const int g = lane / NS;          // 0..6 (lanes 60-63 inactive)
    const bool active = (g < 6);
    const bool loader = (g == 5);
    const bool chain  = (g == 0);

    // hreg[m] = h[17g+2+m] (tap j = depth+2 mapping)
    float hreg[17];
    #pragma unroll
    for (int m = 0; m < 17; ++m) {
        int j = 17*g + 2 + m;
        hreg[m] = (active && j < NT) ? h_s[s*128 + j] : 0.f;
    }
    // transit compensation tap h[17g+19] (0 for g=5 since 104>=100)
    const int jtr = 17*g + 19;
    const float htr = (active && jtr < NT) ? h_s[s*128 + jtr] : 0.f;
    // retire-local low taps
    const float h0r = h_s[s*128 + 0];
    const float h1r = h_s[s*128 + 1];

    // pend init (state at end of virtual step -1): reg k: T = 17g+((k+1)%17)-1
    float pend[17];
    #pragma unroll
    for (int k = 0; k < 17; ++k) {
        int l = (k + 1) % 17;
        int T = 17*g + l - 1;
        pend[k] = (active && T >= 0) ? __half2float(pre[(size_t)T*NS + s]) : 0.f;
    }
    // lookahead: ld[j] first consumed at step t=(j+1)%17 as pre[t+101]
    float ld[17];
    #pragma unroll
    for (int j = 0; j < 17; ++j) {
        int T0 = (j == 16) ? 101 : (102 + j);
        ld[j] = __half2float(pre[(size_t)T0*NS + s]);
    }
    // handoff staging: upA consumed at step 0 (upper pend[16], T=17g+16),
    // upB at step 1 (upper pend[0], T=17g+17)
    float upA = __shfl_down(pend[16], 10);
    float upB = __shfl_down(pend[0], 10);

    const float wl1 = loader ? wp[2*s] : 0.f;      // prop weights, loader-only
    const float wl2 = loader ? wp[2*s + 1] : 0.f;
    const int cc1 = (2*s + 1 < NS) ? (2*s + 1) : 0;
    const int cc2 = (2*s + 2 < NS) ? (2*s + 2) : 0;
    const float Vo  = loadF(V_o, 0, dt);
    const float w0  = loadF(W_sub, 0, dt);
    const float W20 = w0 * w0;

    float nsv = 0.f, n1 = 0.f;                     // ns[t-1][s], ns[t-2][s]
    float vdA = 0.f, vdB = 0.f, vdC = 0.f;         // ns[t-3], ns[t-2], ns[t-4]
    float vc1A = 0.f, vc1B = 0.f;                  // ns[t-3][c1]
    float vc2A = 0.f, vc2B = 0.f;                  // ns[t-3][c2]

    for (int tb = 0; tb < T_DATA; tb += 17) {
        const __half* pb = pre + (size_t)(tb + 118)*NS + s;
        #pragma unroll
        for (int p = 0; p < 17; ++p) {
            const int t = tb + p;
            const int kw = (p + 16) % 17;
            // 1. wrap: consume staged handoff (g=5: rebirth from lookahead)
            pend[kw] = loader ? ld[kw] : upA;
            // 2. transit compensation tap j = 17g+19 with ns[t-4]
            pend[kw] = fmaf(vdC, htr, pend[kw]);
            // 3. refill lookahead (consumed at t+17 as pre[(t+17)+101])
            ld[kw] = __half2float(pb[p*NS]);
            // 4. scatter: tap j = 17g+2+m to reg (p+m)%17 with ns[t-3]
            #pragma unroll
            for (int m = 0; m < 17; ++m) {
                const int k2 = (p + m) % 17;
                pend[k2] = fmaf(vdA, hreg[m], pend[k2]);
            }
            // 5. prop scatter into depth-97 slot (loader lanes only via wl)
            {
                const int kp = (p + 12) % 17;
                pend[kp] = fmaf(wl1, vc1A, pend[kp]);
                pend[kp] = fmaf(wl2, vc2A, pend[kp]);
            }
            // 6. stage handoff for step t+2: upper lane's l=1 slot (post-tap)
            float upN = __shfl_down(pend[(p + 1) % 17], 10);
            // 7. broadcasts for step t+2 (consumed as ns[(t+2)-3])
            float vN   = __shfl(nsv, s);
            float vc1N = __shfl(nsv, cc1);
            float vc2N = __shfl(nsv, cc2);
            // 8. retire (chain lanes' result is the real one)
            float x = fmaf(nsv, h0r, fmaf(n1, h1r, pend[p]));
            float e2 = __builtin_amdgcn_exp2f(x);
            float r  = __builtin_amdgcn_rcpf(e2 + 1.0f);
            float nv = fmaf(-2.0f, r, 1.0f);           // tanh
            float vout = fmaf(nv, W20, Vo);
            if (lane == 0 && t < T_DATA) outV[t] = vout;
            // 9. rotations
            n1 = nsv; nsv = nv;
            vdC = vdA; vdA = vdB; vdB = vN;
            vc1A = vc1B; vc1B = vc1N;
            vc2A = vc2B; vc2B = vc2N;
            upA = upB; upB = upN;
        }
    }
}

__global__ __launch_bounds__(256) void zero_out_kernel(float* out) {
    int i = blockIdx.x * 256 + threadIdx.x;
    if (i < T_DATA + 3000) out[i] = 0.0f;
}

// ---------------------------------------------------------------------------
extern "C" void kernel_launch(void* const* d_in, const int* in_sizes, int n_in,
                              void* d_out, int out_size, void* d_ws, size_t ws_size,
                              hipStream_t stream)
{
    unsigned char* ws = (unsigned char*)d_ws;
    float* out = (float*)d_out;

    static const long EXP[10] = {100000000L, 25000000L, 100, 20000, 5000,
                                 380, 190, 10, 1, 10};
    int idx[10];
    bool ok = (n_in == 10);
    if (ok) {
        bool direct = true;
        for (int k = 0; k < 10; ++k)
            if ((long)in_sizes[k] != EXP[k]) { direct = false; break; }
        if (direct) {
            for (int k = 0; k < 10; ++k) idx[k] = k;
        } else {
            bool used[10] = {false,false,false,false,false,false,false,false,false,false};
            for (int k = 0; k < 10 && ok; ++k) {
                idx[k] = -1;
                for (int j = 0; j < 10; ++j)
                    if (!used[j] && (long)in_sizes[j] == EXP[k]) {
                        idx[k] = j; used[j] = true; break;
                    }
                if (idx[k] < 0) ok = false;
            }
        }
    }
    if (!ok || ws_size < (size_t)WS_NEED) {
        zero_out_kernel<<<208, 256, 0, stream>>>(out);
        return;
    }
    const void* S_e     = d_in[idx[0]];
    const void* S_i     = d_in[idx[1]];
    const void* C_den   = d_in[idx[2]];
    const void* C_syn_e = d_in[idx[3]];
    const void* C_syn_i = d_in[idx[4]];
    const void* W_syn   = d_in[idx[5]];
    const void* Whist   = d_in[idx[6]];
    const void* Wsub0   = d_in[idx[7]];
    const void* V_o     = d_in[idx[8]];
    const void* Wsub1   = d_in[idx[9]];
    int* flags = (int*)(ws + OFF_FLAGS);

    probe_kernel<<<1, 1, 0, stream>>>((const unsigned*)Wsub0,
                                      (const unsigned*)Wsub1, flags);
    prep_kernel<<<1, 256, 0, stream>>>(W_syn, Whist, Wsub0, Wsub1,
                                       C_den, C_syn_e, C_syn_i, flags, ws,
                                       out + T_DATA);
    convf_kernel<<<196, 256, 0, stream>>>(
        S_e, S_i, ws + OFF_AE, ws + OFF_AI,
        (const float*)(ws + OFF_EK), (const float*)(ws + OFF_IK),
        Wsub0, Wsub1, flags, (__half*)(ws + OFF_PRE));
    scan_kernel<<<1, 64, 0, stream>>>(
        (const __half*)(ws + OFF_PRE),
        (const float*)(ws + OFF_H),
        (const float*)(ws + OFF_WP),
        Wsub0, Wsub1, V_o, flags, out);
}